// Round 1
// baseline (489.075 us; speedup 1.0000x reference)
//
#include <hip/hip_runtime.h>
#include <hip/hip_bf16.h>
#include <stdint.h>

// BcosGCNLayer: out[n,o] = lin * |lin| / (R_n * C_o),  lin = z @ W^T
//   R_n = max(||z_n||, eps), C_o = max(||w_o||, eps), eps = 1e-12
// z: [M,512] fp32, W: [512,512] fp32, out: [M,512] fp32.
// Strategy: bf16 MFMA GEMM (threshold is bf16-level), fused z-row-norms,
// W pre-converted to bf16 in d_ws by a tiny prep kernel.

constexpr int KDIM = 512;
constexpr int NDIM = 512;

typedef __attribute__((ext_vector_type(8))) short bf16x8;   // MFMA A/B frag (4 VGPR)
typedef __attribute__((ext_vector_type(4))) float f32x4;    // MFMA C/D frag
typedef __attribute__((ext_vector_type(4))) uint32_t u32x4; // 16B LDS store

__device__ __forceinline__ uint32_t pk_bf16(float a, float b) {
  __hip_bfloat162 h = __float22bfloat162_rn(make_float2(a, b));
  union { __hip_bfloat162 h2; uint32_t u; } c;
  c.h2 = h;
  return c.u;  // low 16 = a, high 16 = b
}

__device__ __forceinline__ void gload_lds16(const void* g, void* lds) {
  // async global->LDS DMA, 16B/lane. LDS dest semantics: wave-uniform base + lane*16,
  // which our (t + 256*i)*16 layout satisfies exactly.
  __builtin_amdgcn_global_load_lds(
      (const __attribute__((address_space(1))) uint32_t*)(uintptr_t)g,
      (__attribute__((address_space(3))) uint32_t*)(uintptr_t)lds,
      16, 0, 0);
}

// ---------- prep: W fp32 -> bf16 (row-major), and 1/max(||w_o||,eps) ----------
__global__ __launch_bounds__(128) void prep_w(const float* __restrict__ w,
                                              unsigned short* __restrict__ wb,
                                              float* __restrict__ cninv) {
  const int row = blockIdx.x;   // 0..511
  const int t   = threadIdx.x;  // 0..127, 4 floats each
  const float* gp = w + (size_t)row * KDIM + t * 4;
  f32x4 v = *(const f32x4*)gp;
  float s = v.x * v.x + v.y * v.y + v.z * v.z + v.w * v.w;

  uint2 p;
  p.x = pk_bf16(v.x, v.y);
  p.y = pk_bf16(v.z, v.w);
  *(uint2*)(wb + (size_t)row * KDIM + t * 4) = p;

  #pragma unroll
  for (int off = 32; off > 0; off >>= 1) s += __shfl_down(s, off, 64);
  __shared__ float red[2];
  if ((t & 63) == 0) red[t >> 6] = s;
  __syncthreads();
  if (t == 0) cninv[row] = 1.0f / fmaxf(sqrtf(red[0] + red[1]), 1e-12f);
}

// ---------- main fused GEMM ----------
// Block tile 128x128, BK=64, 256 threads = 4 waves, each wave 64x64 (4x4 MFMA tiles).
// grid.x = 4 col-blocks (fastest -> L3 reuse of z strip), grid.y = ceil(M/128).
__global__ __launch_bounds__(256) void gemm_bcos(const float* __restrict__ z,
                                                 const unsigned short* __restrict__ wb,
                                                 const float* __restrict__ cninv,
                                                 float* __restrict__ out, int M) {
  __shared__ unsigned short As[128 * 64];  // bf16 z-tile, row-major [128][64]
  __shared__ unsigned short Bs[128 * 64];  // bf16 W-tile, row-major [128][64] (B^T layout)
  __shared__ float rowsq[128];
  __shared__ float rinv[128];

  const int t    = threadIdx.x;
  const int nb   = blockIdx.x;  // 0..3
  const int mb   = blockIdx.y;
  const int w    = t >> 6;
  const int lane = t & 63;
  const int lrow = lane & 15;   // A-frag m / B-frag n / C col
  const int quad = lane >> 4;   // k-chunk select; C row base = quad*4
  const int wm   = (w & 1) * 64;
  const int wn   = (w >> 1) * 64;

  if (t < 128) rowsq[t] = 0.0f;

  f32x4 acc[4][4];
  #pragma unroll
  for (int i = 0; i < 4; ++i)
    #pragma unroll
    for (int j = 0; j < 4; ++j) acc[i][j] = (f32x4)0.0f;

  // A-staging geometry: 1024 groups of 8 floats; 4 groups/thread, rows r = t/8 + 32i
  int rr[4];
  size_t gbase[4];
  #pragma unroll
  for (int i = 0; i < 4; ++i) {
    int gidx = t + 256 * i;
    rr[i] = gidx >> 3;
    int g = gidx & 7;
    int grow = mb * 128 + rr[i];
    if (grow >= M) grow = M - 1;  // tail clamp (store is guarded)
    gbase[i] = (size_t)grow * KDIM + g * 8;
  }

  float sq[4] = {0.f, 0.f, 0.f, 0.f};

  for (int kk = 0; kk < 8; ++kk) {
    const int kbase = kk * 64;
    __syncthreads();

    // B tile: async DMA, 16B x 4 issues/thread
    #pragma unroll
    for (int i = 0; i < 4; ++i) {
      int cidx = t + 256 * i;
      int r = cidx >> 3, c = cidx & 7;
      gload_lds16(wb + ((size_t)(nb * 128 + r) * KDIM + kbase + c * 8), &Bs[cidx * 8]);
    }

    // A tile: fp32 loads -> sumsq -> bf16 pack -> ds_write_b128
    #pragma unroll
    for (int i = 0; i < 4; ++i) {
      const float* gp = z + gbase[i] + kbase;
      f32x4 v0 = *(const f32x4*)gp;
      f32x4 v1 = *(const f32x4*)(gp + 4);
      sq[i] += v0.x * v0.x + v0.y * v0.y + v0.z * v0.z + v0.w * v0.w +
               v1.x * v1.x + v1.y * v1.y + v1.z * v1.z + v1.w * v1.w;
      u32x4 p;
      p.x = pk_bf16(v0.x, v0.y);
      p.y = pk_bf16(v0.z, v0.w);
      p.z = pk_bf16(v1.x, v1.y);
      p.w = pk_bf16(v1.z, v1.w);
      *(u32x4*)&As[(t + 256 * i) * 8] = p;
    }

    __syncthreads();

    // 2 MFMA k-steps of 32
    #pragma unroll
    for (int ks = 0; ks < 2; ++ks) {
      const int k0 = ks * 32 + quad * 8;
      bf16x8 a[4], b[4];
      #pragma unroll
      for (int x = 0; x < 4; ++x) {
        a[x] = *(const bf16x8*)&As[(wm + x * 16 + lrow) * 64 + k0];
        b[x] = *(const bf16x8*)&Bs[(wn + x * 16 + lrow) * 64 + k0];
      }
      #pragma unroll
      for (int mt = 0; mt < 4; ++mt)
        #pragma unroll
        for (int nt = 0; nt < 4; ++nt)
          acc[mt][nt] = __builtin_amdgcn_mfma_f32_16x16x32_bf16(a[mt], b[nt], acc[mt][nt], 0, 0, 0);
    }
  }

  // z row norms: reduce per-thread partials (8 threads per row)
  #pragma unroll
  for (int i = 0; i < 4; ++i) atomicAdd(&rowsq[rr[i]], sq[i]);
  __syncthreads();
  if (t < 128) rinv[t] = 1.0f / fmaxf(sqrtf(rowsq[t]), 1e-12f);
  __syncthreads();

  // epilogue: out = v*|v| * Rinv * Cinv   (C/D layout: col=lane&15, row=quad*4+reg)
  #pragma unroll
  for (int nt = 0; nt < 4; ++nt) {
    const int colg = nb * 128 + wn + nt * 16 + lrow;
    const float cv = cninv[colg];
    #pragma unroll
    for (int mt = 0; mt < 4; ++mt) {
      const int lrm = wm + mt * 16 + quad * 4;
      #pragma unroll
      for (int i = 0; i < 4; ++i) {
        const int rowg = mb * 128 + lrm + i;
        if (rowg < M) {
          const float v = acc[mt][nt][i];
          out[(size_t)rowg * NDIM + colg] = v * fabsf(v) * rinv[lrm + i] * cv;
        }
      }
    }
  }
}

extern "C" void kernel_launch(void* const* d_in, const int* in_sizes, int n_in,
                              void* d_out, int out_size, void* d_ws, size_t ws_size,
                              hipStream_t stream) {
  const float* z = (const float*)d_in[0];
  const float* w = (const float*)d_in[1];
  float* out = (float*)d_out;
  const int M = in_sizes[0] / KDIM;  // 100000

  unsigned short* wb = (unsigned short*)d_ws;                     // 512*512 bf16 = 512 KB
  float* cninv = (float*)((char*)d_ws + (size_t)NDIM * KDIM * 2); // 512 fp32

  prep_w<<<dim3(NDIM), dim3(128), 0, stream>>>(w, wb, cninv);

  dim3 grid(NDIM / 128, (M + 127) / 128);  // (4, 782), col-block fastest
  gemm_bcos<<<grid, dim3(256), 0, stream>>>(z, wb, cninv, out, M);
}